// Round 1
// baseline (188.935 us; speedup 1.0000x reference)
//
#include <hip/hip_runtime.h>

typedef __bf16  bfv8  __attribute__((ext_vector_type(8)));
typedef float   f32x16 __attribute__((ext_vector_type(16)));

#define NTHREADS 256
#define ROWS_PER_BLOCK 256
#define XPAD 36            // 16B-aligned row stride for fp32 X tile in LDS
#define NCHUNK 84          // 80 quadratic 8-wide chunks + 4 linear chunks
#define NSTEP 42           // 672 / 16 GEMM-K steps

// chunk ci -> d index (-1 == linear feature chunk) and e0 (aligned 8-block start)
__host__ __device__ constexpr int chD(int ci){
  return ci < 32 ? (ci >> 2)
       : ci < 56 ? 8  + (ci - 32) / 3
       : ci < 72 ? 16 + ((ci - 56) >> 1)
       : ci < 80 ? 24 + (ci - 72)
       : -1;
}
__host__ __device__ constexpr int chE0(int ci){
  return ci < 32 ? (ci & 3) * 8
       : ci < 56 ? 8  + ((ci - 32) % 3) * 8
       : ci < 72 ? 16 + ((ci - 56) & 1) * 8
       : ci < 80 ? 24
       : (ci - 80) * 8;
}

__device__ inline unsigned short f2bfu(float f){
  __bf16 b = (__bf16)f;
  unsigned short u;
  __builtin_memcpy(&u, &b, 2);
  return u;
}

// ---------------------------------------------------------------------------
// Prep: per mixture k, Cholesky(sigma)=LL^T, M=L^-1, Ainv=M^T M, logdet,
// g = Ainv*mu, cst_k = -log(phi) + 0.5*(D*log(2pi)+logdet) + 0.5*mu^T Ainv mu.
// Pack B (coefficients of the Gram-feature GEMM) fragment-major:
//   Bws[ci*256 + k*8 + j] = bf16 coefficient of feature (ci,j) for mixture k.
// ---------------------------------------------------------------------------
__global__ __launch_bounds__(64) void gmm_prep(
    const float* __restrict__ mus, const float* __restrict__ sigmas,
    const float* __restrict__ phis, unsigned short* __restrict__ Bws,
    float* __restrict__ cstw)
{
  __shared__ float Lm[32][33];
  __shared__ float Mi[32][33];
  __shared__ float Av[32][33];
  __shared__ float gv[32];

  const int k = blockIdx.x;
  const int t = threadIdx.x;

  const float* sg = sigmas + k * 1024;
  for (int i = t; i < 1024; i += 64) Lm[i >> 5][i & 31] = sg[i];
  __syncthreads();

  // Cholesky (lower, in place)
  for (int j = 0; j < 32; ++j){
    if (t == 0) Lm[j][j] = sqrtf(Lm[j][j]);
    __syncthreads();
    if (t > j && t < 32) Lm[t][j] = Lm[t][j] / Lm[j][j];
    __syncthreads();
    const int w = 31 - j;
    for (int idx = t; idx < w * w; idx += 64){
      int i = j + 1 + idx / w;
      int l = j + 1 + idx % w;
      if (l <= i) Lm[i][l] -= Lm[i][j] * Lm[l][j];
    }
    __syncthreads();
  }

  // M = L^-1 (lower), one column per thread
  if (t < 32){
    const int c = t;
    Mi[c][c] = 1.0f / Lm[c][c];
    for (int i = c + 1; i < 32; ++i){
      float s = 0.f;
      for (int tt = c; tt < i; ++tt) s += Lm[i][tt] * Mi[tt][c];
      Mi[i][c] = -s / Lm[i][i];
    }
  }
  __syncthreads();

  // Ainv = M^T M (symmetric)
  for (int idx = t; idx < 1024; idx += 64){
    int d = idx >> 5, e = idx & 31;
    if (e >= d){
      float s = 0.f;
      for (int i = e; i < 32; ++i) s += Mi[i][d] * Mi[i][e];
      Av[d][e] = s; Av[e][d] = s;
    }
  }
  __syncthreads();

  const float* mu = mus + k * 32;
  if (t < 32){
    float s = 0.f;
    for (int e = 0; e < 32; ++e) s += Av[t][e] * mu[e];
    gv[t] = s;
  }
  __syncthreads();

  if (t == 0){
    float hh = 0.f;
    for (int e = 0; e < 32; ++e) hh += mu[e] * gv[e];
    float ld = 0.f;
    for (int j = 0; j < 32; ++j) ld += logf(Lm[j][j]);
    ld *= 2.f;
    // ln(2*pi) = 1.8378770664093453
    cstw[k] = -logf(phis[k]) + 0.5f * (32.f * 1.8378770664093453f + ld) + 0.5f * hh;
  }

  // pack B coefficients
  for (int ci = t; ci < NCHUNK; ci += 64){
    const int d = chD(ci), e0 = chE0(ci);
    for (int j = 0; j < 8; ++j){
      const int e = e0 + j;
      float v;
      if (d < 0)        v = -gv[e];          // linear feature: coeff of x_e
      else if (e < d)   v = 0.f;             // padded / lower-tri: zero coeff
      else if (e == d)  v = 0.5f * Av[d][d]; // 0.5 * diag
      else              v = Av[d][e];        // off-diag (0.5 * 2)
      Bws[ci * 256 + k * 8 + j] = f2bfu(v);
    }
  }
}

// ---------------------------------------------------------------------------
// Main: fused Gram-feature GEMM [N x 672] * [672 x 32] via 32x32x16 bf16 MFMA,
// epilogue = +cst, row-max butterfly over the 32 k-lanes, divide, store.
// ---------------------------------------------------------------------------
__global__ __launch_bounds__(256, 2) void gmm_main(
    const float* __restrict__ X, const unsigned short* __restrict__ Bws,
    const float* __restrict__ cstg, float* __restrict__ out, int N)
{
  __shared__ uint4 ldsBv[2688];                    // 43008 B : B fragments
  __shared__ float Xl[ROWS_PER_BLOCK * XPAD];      // 36864 B : fp32 X tile

  const int tid  = threadIdx.x;
  const int lane = tid & 63;
  const int w    = tid >> 6;
  const int h    = lane >> 5;       // MFMA half: k = h*8 + j
  const int c32  = lane & 31;       // A row within tile / C column (mixture k)
  const int blockRow = blockIdx.x * ROWS_PER_BLOCK;

  // stage B fragments (42 KB, contiguous)
  const uint4* Bg = (const uint4*)Bws;
  for (int i = tid; i < 2688; i += NTHREADS) ldsBv[i] = Bg[i];

  // stage X tile (coalesced float4), zero-fill OOB rows
  for (int i = tid; i < ROWS_PER_BLOCK * 8; i += NTHREADS){
    int lr = i >> 3, c4 = i & 7;
    int gr = blockRow + lr;
    float4 v = make_float4(0.f, 0.f, 0.f, 0.f);
    if (gr < N) v = ((const float4*)X)[gr * 8 + c4];
    *(float4*)&Xl[lr * XPAD + c4 * 4] = v;
  }

  const float cc = cstg[c32];       // per-mixture constant (column of C)
  __syncthreads();

  // lane's two sample rows (rt0, rt1) into registers
  float x0[32], x1[32];
  {
    const float* p0 = &Xl[(w * 64 + c32) * XPAD];
    const float* p1 = p0 + 32 * XPAD;
    #pragma unroll
    for (int q = 0; q < 8; ++q){
      float4 v0 = *(const float4*)(p0 + q * 4);
      float4 v1 = *(const float4*)(p1 + q * 4);
      x0[q*4+0] = v0.x; x0[q*4+1] = v0.y; x0[q*4+2] = v0.z; x0[q*4+3] = v0.w;
      x1[q*4+0] = v1.x; x1[q*4+1] = v1.y; x1[q*4+2] = v1.z; x1[q*4+3] = v1.w;
    }
  }

  f32x16 acc0, acc1;
  #pragma unroll
  for (int i = 0; i < 16; ++i){ acc0[i] = 0.f; acc1[i] = 0.f; }

  const bfv8* Bf = (const bfv8*)ldsBv;

  #pragma unroll
  for (int s = 0; s < NSTEP; ++s){
    // B frag: lane reads its 8 coeffs; layout makes this lane*16B contiguous
    bfv8 bfrag = Bf[(s << 6) + lane];

    const int ca = 2 * s, cb = 2 * s + 1;     // chunk for h=0 / h=1
    const int da = chD(ca), db = chD(cb);
    const int ea = chE0(ca), eb = chE0(cb);

    bfv8 a0, a1;
    float m0 = 1.f, m1 = 1.f;
    if (da >= 0){                              // quad chunks (pairs share type)
      m0 = h ? x1[0] * 0.f + x0[db < 0 ? 0 : db] : x0[da < 0 ? 0 : da];
      m1 = h ? x1[db < 0 ? 0 : db] : x1[da < 0 ? 0 : da];
    }
    #pragma unroll
    for (int j = 0; j < 8; ++j){
      float s0 = h ? x0[eb + j] : x0[ea + j];
      float s1 = h ? x1[eb + j] : x1[ea + j];
      float v0, v1;
      if (da >= 0){ v0 = m0 * s0; v1 = m1 * s1; }
      else        { v0 = s0;      v1 = s1; }
      a0[j] = (__bf16)v0;
      a1[j] = (__bf16)v1;
    }
    acc0 = __builtin_amdgcn_mfma_f32_32x32x16_bf16(a0, bfrag, acc0, 0, 0, 0);
    acc1 = __builtin_amdgcn_mfma_f32_32x32x16_bf16(a1, bfrag, acc1, 0, 0, 0);
  }

  // epilogue: nll = acc + cst ; row-max over 32 k-lanes ; divide ; store
  const int rowBase0 = blockRow + w * 64;
  #pragma unroll
  for (int rt = 0; rt < 2; ++rt){
    float nll[16], mx[16];
    #pragma unroll
    for (int r = 0; r < 16; ++r){
      float nv = (rt == 0 ? acc0[r] : acc1[r]) + cc;
      nll[r] = nv; mx[r] = nv;
    }
    #pragma unroll
    for (int md = 1; md <= 16; md <<= 1){
      #pragma unroll
      for (int r = 0; r < 16; ++r)
        mx[r] = fmaxf(mx[r], __shfl_xor(mx[r], md));
    }
    #pragma unroll
    for (int r = 0; r < 16; ++r){
      int row = (r & 3) + 8 * (r >> 2) + 4 * h;   // verified C/D mapping
      int n = rowBase0 + rt * 32 + row;
      if (n < N) out[n * 32 + c32] = nll[r] * __builtin_amdgcn_rcpf(mx[r]);
    }
  }
}

extern "C" void kernel_launch(void* const* d_in, const int* in_sizes, int n_in,
                              void* d_out, int out_size, void* d_ws, size_t ws_size,
                              hipStream_t stream)
{
  const float* X      = (const float*)d_in[0];
  const float* mus    = (const float*)d_in[1];
  const float* sigmas = (const float*)d_in[2];
  const float* phis   = (const float*)d_in[3];
  float* out = (float*)d_out;
  const int N = in_sizes[0] / 32;

  unsigned short* Bws = (unsigned short*)d_ws;
  float* cstw = (float*)((char*)d_ws + NCHUNK * 32 * 8 * 2);   // +43008 B

  gmm_prep<<<32, 64, 0, stream>>>(mus, sigmas, phis, Bws, cstw);

  const int nb = (N + ROWS_PER_BLOCK - 1) / ROWS_PER_BLOCK;
  gmm_main<<<nb, NTHREADS, 0, stream>>>(X, Bws, cstw, out, N);
}

// Round 2
// 157.085 us; speedup vs baseline: 1.2028x; 1.2028x over previous
//
#include <hip/hip_runtime.h>
#include <hip/hip_bf16.h>

typedef __bf16  bfv8   __attribute__((ext_vector_type(8)));
typedef float   f32x16 __attribute__((ext_vector_type(16)));

#define NSTEP  42
#define NCHUNK 84

// ---------------------------------------------------------------------------
// Step tables: step s consumes K-slots 0-7 (h=0, chunk A) and 8-15 (h=1, chunk
// B). Chunks are paired so both halves share the same source block e0 for
// s<40 (only the multiplier x_d differs) -> no per-element h-select.
// Chunk (d,e0): features x_d * x_{e0+j}, j=0..7. d=-1 => linear features.
// ---------------------------------------------------------------------------
__host__ __device__ constexpr int stepDA(int s){
  return s < 4 ? 2*s : s < 12 ? 2*(s-4) : s < 24 ? 2*(s-12) : s < 40 ? 2*(s-24) : -1;
}
__host__ __device__ constexpr int stepDB(int s){
  return s < 40 ? stepDA(s) + 1 : -1;
}
__host__ __device__ constexpr int stepEA(int s){
  return s < 4 ? 0 : s < 12 ? 8 : s < 24 ? 16 : s < 40 ? 24 : (s == 40 ? 0 : 16);
}
__host__ __device__ constexpr int stepEB(int s){
  return s < 40 ? stepEA(s) : (s == 40 ? 8 : 24);
}

__device__ inline unsigned short f2bfu(float f){
  __bf16 b = (__bf16)f;
  unsigned short u;
  __builtin_memcpy(&u, &b, 2);
  return u;
}

// ---------------------------------------------------------------------------
// Prep: parallel Cholesky + two parallel triangular substitutions.
// 256 threads/block, one block per mixture. One __syncthreads per serial step.
// Thread cell map: (i = (t>>5)*4+p, l = t&31), p=0..3.
// ---------------------------------------------------------------------------
__global__ __launch_bounds__(256) void gmm_prep(
    const float* __restrict__ mus, const float* __restrict__ sigmas,
    const float* __restrict__ phis, unsigned short* __restrict__ Bws,
    float* __restrict__ cstw)
{
  __shared__ float Lm[32][33];   // working copy of sigma / cholesky scratch
  __shared__ float Lc[32][33];   // scaled Cholesky factor L
  __shared__ float Yv[32][33];   // RHS buffer -> ends as Sigma^-1
  __shared__ float dinv[32];     // 1/L[j][j]
  __shared__ float dj[32];       // pivot d_j (for logdet)
  __shared__ float gv[32];       // Sigma^-1 mu
  __shared__ float muL[32];

  const int t  = threadIdx.x;
  const int k  = blockIdx.x;
  const int c  = t & 31;
  const int rg = t >> 5;         // 0..7

  // ---- load sigma (coalesced float4), init Y = I, stage mu ----
  {
    float4 v = ((const float4*)(sigmas + k * 1024))[t];
    int r = t >> 3, c0 = (t & 7) * 4;
    Lm[r][c0] = v.x; Lm[r][c0+1] = v.y; Lm[r][c0+2] = v.z; Lm[r][c0+3] = v.w;
  }
  #pragma unroll
  for (int p = 0; p < 4; ++p){
    int r = rg * 4 + p;
    Yv[r][c] = (r == c) ? 1.f : 0.f;
  }
  if (t < 32) muL[t] = mus[k * 32 + t];
  __syncthreads();

  // ---- Cholesky: outer-product form, 1 sync per step ----
  // update: Lm[i][l] -= Lm[i][j]*Lm[l][j]/d  (reads only frozen column j)
  for (int j = 0; j < 32; ++j){
    float d    = Lm[j][j];
    float rinv = __builtin_amdgcn_rcpf(d);
    float rs   = rsqrtf(d);
    #pragma unroll
    for (int p = 0; p < 4; ++p){
      int i = rg * 4 + p;
      if (c > j && i >= c) Lm[i][c] -= Lm[i][j] * Lm[c][j] * rinv;
      if (c == j && i >= j){
        Lc[i][j] = Lm[i][j] * rs;
        if (i == j){ dinv[j] = rs; dj[j] = d; }
      }
    }
    __syncthreads();
  }

  // ---- forward solve L*Y = I (raw-residual form, 1 sync per step) ----
  for (int i = 0; i < 32; ++i){
    float yv = Yv[i][c] * dinv[i];      // row i frozen this step
    #pragma unroll
    for (int p = 0; p < 4; ++p){
      int r = rg * 4 + p;
      if (r > i) Yv[r][c] -= Lc[r][i] * yv;
    }
    __syncthreads();
  }
  // finalize y = L^-1 (row scale)
  #pragma unroll
  for (int p = 0; p < 4; ++p){ int r = rg * 4 + p; Yv[r][c] *= dinv[r]; }
  __syncthreads();

  // ---- backward solve L^T * X = y ; X = Sigma^-1 ----
  for (int i = 31; i >= 0; --i){
    float xv = Yv[i][c] * dinv[i];
    #pragma unroll
    for (int p = 0; p < 4; ++p){
      int r = rg * 4 + p;
      if (r < i) Yv[r][c] -= Lc[i][r] * xv;
    }
    __syncthreads();
  }
  #pragma unroll
  for (int p = 0; p < 4; ++p){ int r = rg * 4 + p; Yv[r][c] *= dinv[r]; }
  __syncthreads();

  // ---- g = Sigma^-1 mu ----
  if (t < 32){
    float s = 0.f;
    #pragma unroll
    for (int e = 0; e < 32; ++e) s += Yv[t][e] * muL[e];
    gv[t] = s;
  }
  __syncthreads();

  // ---- cst_k ----
  if (t == 0){
    float hh = 0.f, ld = 0.f;
    for (int e = 0; e < 32; ++e) hh += muL[e] * gv[e];
    for (int j2 = 0; j2 < 32; ++j2) ld += logf(dj[j2]);
    cstw[k] = -logf(phis[k]) + 0.5f * (32.f * 1.8378770664093453f + ld) + 0.5f * hh;
  }

  // ---- pack B coefficients, fragment-major: uint4 index = ci*32 + k ----
  if (t < NCHUNK){
    int s2 = t >> 1, hb = t & 1;
    int d  = hb ? stepDB(s2) : stepDA(s2);
    int e0 = hb ? stepEB(s2) : stepEA(s2);
    unsigned short u8[8];
    for (int j = 0; j < 8; ++j){
      int e = e0 + j;
      float v;
      if (d < 0)       v = -gv[e];            // linear: coeff of x_e
      else if (e < d)  v = 0.f;               // lower-tri pad
      else if (e == d) v = 0.5f * Yv[d][d];   // diag: 0.5*S_dd
      else             v = Yv[d][e];          // off-diag (0.5*2)
      u8[j] = f2bfu(v);
    }
    uint4 pk; __builtin_memcpy(&pk, u8, 16);
    ((uint4*)Bws)[t * 32 + k] = pk;
  }
}

// ---------------------------------------------------------------------------
// Main: fused Gram-feature GEMM [N x 672] * [672 x 32] via 32x32x16 bf16 MFMA.
// 512 threads = 8 waves, 32 rows/wave (one accumulator), 256 rows/block.
// x lives in 32 VGPRs, loaded straight from global (no X LDS -> 43KB LDS,
// 3 blocks/CU). A-fragments: 8 fp32 muls + 4 packed bf16 converts per step.
// ---------------------------------------------------------------------------
__global__ __launch_bounds__(512, 4) void gmm_main(
    const float* __restrict__ X, const unsigned short* __restrict__ Bws,
    const float* __restrict__ cstg, float* __restrict__ out, int N)
{
  __shared__ uint4 ldsB[NSTEP * 64];   // 43008 B : B fragments

  const int tid  = threadIdx.x;
  const int lane = tid & 63;
  const int wv   = tid >> 6;          // wave 0..7
  const int h    = lane >> 5;         // K-half
  const int c32  = lane & 31;         // A row in tile / C column (mixture)
  const int blockRow = blockIdx.x * 256;

  // stage B fragments (contiguous 43 KB)
  const uint4* Bg = (const uint4*)Bws;
  for (int i = tid; i < NSTEP * 64; i += 512) ldsB[i] = Bg[i];

  // lane's sample row (both halves hold the same 32 rows; loads coalesce/L1)
  const int rowi = blockRow + wv * 32 + c32;
  const int rowc = rowi < N ? rowi : N - 1;
  float x[32];
  {
    const float4* xp = (const float4*)(X + (size_t)rowc * 32);
    #pragma unroll
    for (int q = 0; q < 8; ++q){
      float4 v = xp[q];
      x[q*4+0] = v.x; x[q*4+1] = v.y; x[q*4+2] = v.z; x[q*4+3] = v.w;
    }
  }
  const float cc = cstg[c32];
  __syncthreads();

  f32x16 acc;
  #pragma unroll
  for (int i = 0; i < 16; ++i) acc[i] = 0.f;

  union BF8 { unsigned int u[4]; bfv8 v; };
  const bfv8* Bf = (const bfv8*)ldsB;

  #pragma unroll
  for (int s = 0; s < NSTEP; ++s){
    bfv8 bfrag = Bf[(s << 6) + lane];          // ds_read_b128, conflict-free

    constexpr int dummy = 0; (void)dummy;
    const int da = stepDA(s), db = stepDB(s);
    const int ea = stepEA(s), eb = stepEB(s);

    BF8 af;
    if (da >= 0){
      // quadratic pair: same e0 both halves, only the multiplier differs
      float m = h ? x[db] : x[da];             // 1 cndmask
      #pragma unroll
      for (int jj = 0; jj < 4; ++jj){
        float lo = m * x[ea + 2*jj];
        float hi = m * x[ea + 2*jj + 1];
        __hip_bfloat162 p = __float22bfloat162_rn(make_float2(lo, hi));
        __builtin_memcpy(&af.u[jj], &p, 4);
      }
    } else {
      // linear steps (2 of 42): h-select the source block
      #pragma unroll
      for (int jj = 0; jj < 4; ++jj){
        float lo = h ? x[eb + 2*jj]     : x[ea + 2*jj];
        float hi = h ? x[eb + 2*jj + 1] : x[ea + 2*jj + 1];
        __hip_bfloat162 p = __float22bfloat162_rn(make_float2(lo, hi));
        __builtin_memcpy(&af.u[jj], &p, 4);
      }
    }
    acc = __builtin_amdgcn_mfma_f32_32x32x16_bf16(af.v, bfrag, acc, 0, 0, 0);
  }

  // epilogue: nll = acc + cst ; row-max over the 32 k-lanes ; divide ; store
  float nll[16], mx[16];
  #pragma unroll
  for (int r = 0; r < 16; ++r){
    float nv = acc[r] + cc;
    nll[r] = nv; mx[r] = nv;
  }
  #pragma unroll
  for (int md = 1; md <= 16; md <<= 1){
    #pragma unroll
    for (int r = 0; r < 16; ++r)
      mx[r] = fmaxf(mx[r], __shfl_xor(mx[r], md));
  }
  #pragma unroll
  for (int r = 0; r < 16; ++r){
    int row = (r & 3) + 8 * (r >> 2) + 4 * h;   // verified C/D mapping
    int n = blockRow + wv * 32 + row;
    if (n < N) out[(size_t)n * 32 + c32] = nll[r] * __builtin_amdgcn_rcpf(mx[r]);
  }
}

extern "C" void kernel_launch(void* const* d_in, const int* in_sizes, int n_in,
                              void* d_out, int out_size, void* d_ws, size_t ws_size,
                              hipStream_t stream)
{
  const float* X      = (const float*)d_in[0];
  const float* mus    = (const float*)d_in[1];
  const float* sigmas = (const float*)d_in[2];
  const float* phis   = (const float*)d_in[3];
  float* out = (float*)d_out;
  const int N = in_sizes[0] / 32;

  unsigned short* Bws = (unsigned short*)d_ws;
  float* cstw = (float*)((char*)d_ws + NCHUNK * 256 * 2);   // +43008 B

  gmm_prep<<<32, 256, 0, stream>>>(mus, sigmas, phis, Bws, cstw);

  const int nb = (N + 255) / 256;
  gmm_main<<<nb, 512, 0, stream>>>(X, Bws, cstw, out, N);
}

// Round 3
// 113.910 us; speedup vs baseline: 1.6586x; 1.3790x over previous
//
#include <hip/hip_runtime.h>

typedef _Float16 f16x8  __attribute__((ext_vector_type(8)));
typedef _Float16 h2v    __attribute__((ext_vector_type(2)));
typedef float    f32x16 __attribute__((ext_vector_type(16)));

#define NSTEP  42
#define NCHUNK 84

// ---------------------------------------------------------------------------
// Step tables (same as R2, verified): step s uses K-slots 0-7 (h=0, chunk A)
// and 8-15 (h=1, chunk B). Quadratic pairs share e0; multipliers x[da]/x[db]
// are the two halves of one packed half2 register (da even, db=da+1).
// ---------------------------------------------------------------------------
__host__ __device__ constexpr int stepDA(int s){
  return s < 4 ? 2*s : s < 12 ? 2*(s-4) : s < 24 ? 2*(s-12) : s < 40 ? 2*(s-24) : -1;
}
__host__ __device__ constexpr int stepDB(int s){
  return s < 40 ? stepDA(s) + 1 : -1;
}
__host__ __device__ constexpr int stepEA(int s){
  return s < 4 ? 0 : s < 12 ? 8 : s < 24 ? 16 : s < 40 ? 24 : (s == 40 ? 0 : 16);
}
__host__ __device__ constexpr int stepEB(int s){
  return s < 40 ? stepEA(s) : (s == 40 ? 8 : 24);
}

__device__ inline float rdlane(float v, int i){
  union { float f; int u; } a, r;
  a.f = v;
  r.u = __builtin_amdgcn_readlane(a.u, i);
  return r.f;
}
__device__ inline unsigned short f2h(float f){
  _Float16 h = (_Float16)f;
  unsigned short u; __builtin_memcpy(&u, &h, 2);
  return u;
}
__device__ inline unsigned pkmulh2(unsigned a, unsigned b){
  h2v x, y; __builtin_memcpy(&x, &a, 4); __builtin_memcpy(&y, &b, 4);
  h2v z = x * y;                        // v_pk_mul_f16
  unsigned r; __builtin_memcpy(&r, &z, 4);
  return r;
}

// ---------------------------------------------------------------------------
// Prep v3: one 64-lane wave per mixture, ZERO barriers in the serial math.
// Column-per-lane register layout (c = lane&31; lanes 32-63 mirror 0-31).
// Cross-lane via v_readlane (compile-time indices -> full unroll).
// ---------------------------------------------------------------------------
__global__ __launch_bounds__(64) void gmm_prep(
    const float* __restrict__ mus, const float* __restrict__ sigmas,
    const float* __restrict__ phis, unsigned short* __restrict__ Bws,
    float* __restrict__ cstw)
{
  __shared__ float Sld[32 * 33];   // Sigma^-1
  __shared__ float gld[32];        // Sigma^-1 mu

  const int k    = blockIdx.x;
  const int lane = threadIdx.x;
  const int c    = lane & 31;

  // load column c of sigma (full symmetric matrix): a[i] = Sigma[i][c]
  float a[32];
  #pragma unroll
  for (int i = 0; i < 32; ++i) a[i] = sigmas[k * 1024 + i * 32 + c];

  float drs = 0.f, dpiv = 1.f;

  // ---- symmetric-Schur Cholesky, column frozen at j==c ----
  #pragma unroll
  for (int j = 0; j < 32; ++j){
    float m    = a[j];                      // A[j][c] == A[c][j]
    float d    = rdlane(a[j], j);           // pivot A[j][j]
    float rs   = rsqrtf(d);
    float rinv = rs * rs;
    if (c == j){ drs = rs; dpiv = d; }
    float mr = m * rinv;
    #pragma unroll
    for (int t = j + 1; t < 32; ++t){
      float s_t = rdlane(a[j], t);          // A[t][j]
      float upd = a[t] - s_t * mr;
      a[t] = (c > j) ? upd : a[t];
    }
  }

  // L column c in place: l[i] = a[i]*drs (i>=c), else 0
  #pragma unroll
  for (int i = 0; i < 32; ++i) a[i] = (i >= c) ? a[i] * drs : 0.f;

  // ---- forward solve L y = e_c ----
  float r[32];
  #pragma unroll
  for (int i = 0; i < 32; ++i) r[i] = (i == c) ? 1.f : 0.f;
  #pragma unroll
  for (int i = 0; i < 32; ++i){
    float di = rdlane(drs, i);              // 1/L[i][i]
    float yi = r[i] * di;
    r[i] = yi;
    #pragma unroll
    for (int t = i + 1; t < 32; ++t)
      r[t] -= rdlane(a[t], i) * yi;         // L[t][i] = lane i's a[t]
  }
  // ---- backward solve L^T x = y ; r becomes Sigma^-1 column c ----
  #pragma unroll
  for (int i = 31; i >= 0; --i){
    float di = rdlane(drs, i);
    float xi = r[i] * di;
    r[i] = xi;
    #pragma unroll
    for (int t = 0; t < i; ++t)
      r[t] -= rdlane(a[i], t) * xi;         // L[i][t] = lane t's a[i]
  }

  // ---- g_c = (Sigma^-1 mu)[c] via symmetry: column c dot mu ----
  float muc = mus[k * 32 + c];
  float g = 0.f;
  #pragma unroll
  for (int i = 0; i < 32; ++i) g += r[i] * rdlane(muc, i);

  // ---- hh = mu^T g, logdet = sum log d_j (32-lane butterflies) ----
  float hh = muc * g;
  float ll = logf(dpiv);
  #pragma unroll
  for (int md = 1; md <= 16; md <<= 1){
    hh += __shfl_xor(hh, md);
    ll += __shfl_xor(ll, md);
  }
  if (lane == 0)
    cstw[k] = -logf(phis[k]) + 0.5f * (32.f * 1.8378770664093453f + ll) + 0.5f * hh;

  // ---- stash Sinv + g to LDS for packing ----
  if (lane < 32){
    #pragma unroll
    for (int i = 0; i < 32; ++i) Sld[i * 33 + c] = r[i];
    gld[c] = g;
  }
  __syncthreads();   // single-wave block: cheap, orders LDS

  // ---- pack B coefficients (fp16), fragment-major: uint4 idx = ci*32 + k ----
  for (int ci = lane; ci < NCHUNK; ci += 64){
    int s2 = ci >> 1, hb = ci & 1;
    int d  = hb ? stepDB(s2) : stepDA(s2);
    int e0 = hb ? stepEB(s2) : stepEA(s2);
    unsigned short u8[8];
    for (int j = 0; j < 8; ++j){
      int e = e0 + j;
      float v;
      if (d < 0)       v = -gld[e];              // linear: coeff of x_e
      else if (e < d)  v = 0.f;                  // lower-tri pad
      else if (e == d) v = 0.5f * Sld[d * 33 + d];
      else             v = Sld[d * 33 + e];      // off-diag (0.5*2)
      u8[j] = f2h(v);
    }
    uint4 pk; __builtin_memcpy(&pk, u8, 16);
    ((uint4*)Bws)[ci * 32 + k] = pk;
  }
}

// ---------------------------------------------------------------------------
// Main v3: fp16 MFMA, 256 threads = 4 waves, 2 row-tiles/wave (256 rows/blk).
// x kept as 16 packed half2 VGPRs per tile; A-fragment = 1 v_perm_b32
// (broadcast multiplier) + 4 v_pk_mul_f16 per tile per step.
// ---------------------------------------------------------------------------
__global__ __launch_bounds__(256, 3) void gmm_main(
    const float* __restrict__ X, const unsigned short* __restrict__ Bws,
    const float* __restrict__ cstg, float* __restrict__ out, int N)
{
  __shared__ uint4 ldsB[NSTEP * 64];   // 43008 B

  const int tid  = threadIdx.x;
  const int lane = tid & 63;
  const int wv   = tid >> 6;          // wave 0..3
  const int h    = lane >> 5;         // K-half
  const int c32  = lane & 31;         // A row in tile / C column (mixture)
  const int blockRow = blockIdx.x * 256;

  // stage B fragments
  const uint4* Bg = (const uint4*)Bws;
  for (int i = tid; i < NSTEP * 64; i += 256) ldsB[i] = Bg[i];

  // byte-selector: duplicate low half (h=0) or high half (h=1) of a half2 reg
  const unsigned sel = h ? 0x03020302u : 0x01000100u;

  // two row-tiles per wave: rows wv*64+c32 and +32
  const int r0 = blockRow + wv * 64 + c32;
  const int r1 = r0 + 32;
  const int r0c = r0 < N ? r0 : N - 1;
  const int r1c = r1 < N ? r1 : N - 1;

  unsigned xu0[16], xu1[16];
  {
    const float4* p0 = (const float4*)(X + (size_t)r0c * 32);
    const float4* p1 = (const float4*)(X + (size_t)r1c * 32);
    #pragma unroll
    for (int q = 0; q < 8; ++q){
      float4 v0 = p0[q], v1 = p1[q];
      unsigned short h00 = f2h(v0.x), h01 = f2h(v0.y), h02 = f2h(v0.z), h03 = f2h(v0.w);
      unsigned short h10 = f2h(v1.x), h11 = f2h(v1.y), h12 = f2h(v1.z), h13 = f2h(v1.w);
      xu0[q*2+0] = (unsigned)h00 | ((unsigned)h01 << 16);
      xu0[q*2+1] = (unsigned)h02 | ((unsigned)h03 << 16);
      xu1[q*2+0] = (unsigned)h10 | ((unsigned)h11 << 16);
      xu1[q*2+1] = (unsigned)h12 | ((unsigned)h13 << 16);
    }
  }
  const float cc = cstg[c32];
  __syncthreads();

  f32x16 acc0, acc1;
  #pragma unroll
  for (int i = 0; i < 16; ++i){ acc0[i] = 0.f; acc1[i] = 0.f; }

  union AF { unsigned u[4]; f16x8 v; };
  const f16x8* Bf = (const f16x8*)ldsB;

  #pragma unroll
  for (int s = 0; s < NSTEP; ++s){
    f16x8 bfrag = Bf[(s << 6) + lane];        // ds_read_b128, conflict-free

    AF a0, a1;
    if (s < 40){
      const int p = stepDA(s) >> 1;           // half2 reg holding (x[da],x[db])
      const int e = stepEA(s) >> 1;
      unsigned m0 = __builtin_amdgcn_perm(xu0[p], xu0[p], sel);
      unsigned m1 = __builtin_amdgcn_perm(xu1[p], xu1[p], sel);
      #pragma unroll
      for (int jj = 0; jj < 4; ++jj){
        a0.u[jj] = pkmulh2(m0, xu0[e + jj]);
        a1.u[jj] = pkmulh2(m1, xu1[e + jj]);
      }
    } else {
      const int ea = stepEA(s) >> 1, eb = stepEB(s) >> 1;
      #pragma unroll
      for (int jj = 0; jj < 4; ++jj){
        a0.u[jj] = h ? xu0[eb + jj] : xu0[ea + jj];
        a1.u[jj] = h ? xu1[eb + jj] : xu1[ea + jj];
      }
    }
    acc0 = __builtin_amdgcn_mfma_f32_32x32x16_f16(a0.v, bfrag, acc0, 0, 0, 0);
    acc1 = __builtin_amdgcn_mfma_f32_32x32x16_f16(a1.v, bfrag, acc1, 0, 0, 0);
  }

  // epilogue per tile: +cst, 32-lane column max, divide, store
  #pragma unroll
  for (int rt = 0; rt < 2; ++rt){
    float nll[16], mx[16];
    #pragma unroll
    for (int r = 0; r < 16; ++r){
      float nv = (rt == 0 ? acc0[r] : acc1[r]) + cc;
      nll[r] = nv; mx[r] = nv;
    }
    #pragma unroll
    for (int md = 1; md <= 16; md <<= 1){
      #pragma unroll
      for (int r = 0; r < 16; ++r)
        mx[r] = fmaxf(mx[r], __shfl_xor(mx[r], md));
    }
    const int rowBase = blockRow + wv * 64 + rt * 32;
    #pragma unroll
    for (int r = 0; r < 16; ++r){
      int row = (r & 3) + 8 * (r >> 2) + 4 * h;   // verified C/D mapping
      int n = rowBase + row;
      if (n < N) out[(size_t)n * 32 + c32] = nll[r] * __builtin_amdgcn_rcpf(mx[r]);
    }
  }
}

extern "C" void kernel_launch(void* const* d_in, const int* in_sizes, int n_in,
                              void* d_out, int out_size, void* d_ws, size_t ws_size,
                              hipStream_t stream)
{
  const float* X      = (const float*)d_in[0];
  const float* mus    = (const float*)d_in[1];
  const float* sigmas = (const float*)d_in[2];
  const float* phis   = (const float*)d_in[3];
  float* out = (float*)d_out;
  const int N = in_sizes[0] / 32;

  unsigned short* Bws = (unsigned short*)d_ws;
  float* cstw = (float*)((char*)d_ws + NCHUNK * 256 * 2);   // +43008 B

  gmm_prep<<<32, 64, 0, stream>>>(mus, sigmas, phis, Bws, cstw);

  const int nb = (N + 255) / 256;
  gmm_main<<<nb, 256, 0, stream>>>(X, Bws, cstw, out, N);
}

// Round 5
// 108.315 us; speedup vs baseline: 1.7443x; 1.0517x over previous
//
#include <hip/hip_runtime.h>

typedef _Float16 f16x8  __attribute__((ext_vector_type(8)));
typedef _Float16 h2v    __attribute__((ext_vector_type(2)));
typedef float    f32x16 __attribute__((ext_vector_type(16)));
typedef unsigned u32x16 __attribute__((ext_vector_type(16)));

#define NSTEP  42
#define NCHUNK 84

// ---------------------------------------------------------------------------
// Step tables (verified R2/R3): step s uses K-slots 0-7 (h=0, chunk A) and
// 8-15 (h=1, chunk B). Quadratic pairs share e0; multipliers x[da]/x[db] are
// the two halves of one packed half2 register (da even, db=da+1).
// ---------------------------------------------------------------------------
__host__ __device__ constexpr int stepDA(int s){
  return s < 4 ? 2*s : s < 12 ? 2*(s-4) : s < 24 ? 2*(s-12) : s < 40 ? 2*(s-24) : -1;
}
__host__ __device__ constexpr int stepDB(int s){
  return s < 40 ? stepDA(s) + 1 : -1;
}
__host__ __device__ constexpr int stepEA(int s){
  return s < 4 ? 0 : s < 12 ? 8 : s < 24 ? 16 : s < 40 ? 24 : (s == 40 ? 0 : 16);
}
__host__ __device__ constexpr int stepEB(int s){
  return s < 40 ? stepEA(s) : (s == 40 ? 8 : 24);
}

__device__ inline float rdlane(float v, int i){
  union { float f; int u; } a, r;
  a.f = v;
  r.u = __builtin_amdgcn_readlane(a.u, i);
  return r.f;
}
__device__ inline unsigned short f2h(float f){
  _Float16 h = (_Float16)f;
  unsigned short u; __builtin_memcpy(&u, &h, 2);
  return u;
}
__device__ inline unsigned pkmulh2(unsigned a, unsigned b){
  h2v x, y; __builtin_memcpy(&x, &a, 4); __builtin_memcpy(&y, &b, 4);
  h2v z = x * y;                        // v_pk_mul_f16
  unsigned r; __builtin_memcpy(&r, &z, 4);
  return r;
}
__device__ inline unsigned pkrtz(float lo, float hi){
  auto p = __builtin_amdgcn_cvt_pkrtz(lo, hi);   // __fp16 x2 vector
  unsigned u; __builtin_memcpy(&u, &p, 4);
  return u;
}

// ---------------------------------------------------------------------------
// Prep (byte-identical to R3): one 64-lane wave per mixture, zero barriers.
// ---------------------------------------------------------------------------
__global__ __launch_bounds__(64) void gmm_prep(
    const float* __restrict__ mus, const float* __restrict__ sigmas,
    const float* __restrict__ phis, unsigned short* __restrict__ Bws,
    float* __restrict__ cstw)
{
  __shared__ float Sld[32 * 33];   // Sigma^-1
  __shared__ float gld[32];        // Sigma^-1 mu

  const int k    = blockIdx.x;
  const int lane = threadIdx.x;
  const int c    = lane & 31;

  float a[32];
  #pragma unroll
  for (int i = 0; i < 32; ++i) a[i] = sigmas[k * 1024 + i * 32 + c];

  float drs = 0.f, dpiv = 1.f;

  // symmetric-Schur Cholesky, column frozen at j==c
  #pragma unroll
  for (int j = 0; j < 32; ++j){
    float m    = a[j];
    float d    = rdlane(a[j], j);
    float rs   = rsqrtf(d);
    float rinv = rs * rs;
    if (c == j){ drs = rs; dpiv = d; }
    float mr = m * rinv;
    #pragma unroll
    for (int t = j + 1; t < 32; ++t){
      float s_t = rdlane(a[j], t);
      float upd = a[t] - s_t * mr;
      a[t] = (c > j) ? upd : a[t];
    }
  }

  #pragma unroll
  for (int i = 0; i < 32; ++i) a[i] = (i >= c) ? a[i] * drs : 0.f;

  // forward solve L y = e_c
  float r[32];
  #pragma unroll
  for (int i = 0; i < 32; ++i) r[i] = (i == c) ? 1.f : 0.f;
  #pragma unroll
  for (int i = 0; i < 32; ++i){
    float di = rdlane(drs, i);
    float yi = r[i] * di;
    r[i] = yi;
    #pragma unroll
    for (int t = i + 1; t < 32; ++t)
      r[t] -= rdlane(a[t], i) * yi;
  }
  // backward solve L^T x = y
  #pragma unroll
  for (int i = 31; i >= 0; --i){
    float di = rdlane(drs, i);
    float xi = r[i] * di;
    r[i] = xi;
    #pragma unroll
    for (int t = 0; t < i; ++t)
      r[t] -= rdlane(a[i], t) * xi;
  }

  float muc = mus[k * 32 + c];
  float g = 0.f;
  #pragma unroll
  for (int i = 0; i < 32; ++i) g += r[i] * rdlane(muc, i);

  float hh = muc * g;
  float ll = logf(dpiv);
  #pragma unroll
  for (int md = 1; md <= 16; md <<= 1){
    hh += __shfl_xor(hh, md);
    ll += __shfl_xor(ll, md);
  }
  if (lane == 0)
    cstw[k] = -logf(phis[k]) + 0.5f * (32.f * 1.8378770664093453f + ll) + 0.5f * hh;

  if (lane < 32){
    #pragma unroll
    for (int i = 0; i < 32; ++i) Sld[i * 33 + c] = r[i];
    gld[c] = g;
  }
  __syncthreads();

  for (int ci = lane; ci < NCHUNK; ci += 64){
    int s2 = ci >> 1, hb = ci & 1;
    int d  = hb ? stepDB(s2) : stepDA(s2);
    int e0 = hb ? stepEB(s2) : stepEA(s2);
    unsigned short u8[8];
    for (int j = 0; j < 8; ++j){
      int e = e0 + j;
      float v;
      if (d < 0)       v = -gld[e];
      else if (e < d)  v = 0.f;
      else if (e == d) v = 0.5f * Sld[d * 33 + d];
      else             v = Sld[d * 33 + e];
      u8[j] = f2h(v);
    }
    uint4 pk; __builtin_memcpy(&pk, u8, 16);
    ((uint4*)Bws)[ci * 32 + k] = pk;
  }
}

// ---------------------------------------------------------------------------
// Main v4b: template-unrolled steps (all indices are literals at
// instantiation -> arrays CANNOT be demoted to scratch). 512 threads =
// 8 waves, 1 row-tile per wave, 256 rows/block. ~70 VGPR, 3 blocks/CU.
// ---------------------------------------------------------------------------
union AF8 { unsigned u[4]; f16x8 v; };

template<int S>
__device__ inline void gstep(const f16x8* __restrict__ Bf, int lane, int h,
                             unsigned sel, const u32x16& xu, f32x16& acc)
{
  f16x8 b = Bf[(S << 6) + lane];            // ds_read_b128, literal offset
  AF8 a;
  if constexpr (S < 40){
    constexpr int p = stepDA(S) >> 1;       // half2 reg holding (x[da],x[db])
    constexpr int e = stepEA(S) >> 1;
    unsigned m = __builtin_amdgcn_perm(xu[p], xu[p], sel);
    a.u[0] = pkmulh2(m, xu[e + 0]);
    a.u[1] = pkmulh2(m, xu[e + 1]);
    a.u[2] = pkmulh2(m, xu[e + 2]);
    a.u[3] = pkmulh2(m, xu[e + 3]);
  } else {
    constexpr int ea = stepEA(S) >> 1;
    constexpr int eb = stepEB(S) >> 1;
    a.u[0] = h ? xu[eb + 0] : xu[ea + 0];
    a.u[1] = h ? xu[eb + 1] : xu[ea + 1];
    a.u[2] = h ? xu[eb + 2] : xu[ea + 2];
    a.u[3] = h ? xu[eb + 3] : xu[ea + 3];
  }
  acc = __builtin_amdgcn_mfma_f32_32x32x16_f16(a.v, b, acc, 0, 0, 0);
}

template<int S>
__device__ inline void gsteps(const f16x8* __restrict__ Bf, int lane, int h,
                              unsigned sel, const u32x16& xu, f32x16& acc)
{
  if constexpr (S < NSTEP){
    gstep<S>(Bf, lane, h, sel, xu, acc);
    gsteps<S + 1>(Bf, lane, h, sel, xu, acc);
  }
}

__global__ __launch_bounds__(512, 4) void gmm_main(
    const float* __restrict__ X, const unsigned short* __restrict__ Bws,
    const float* __restrict__ cstg, float* __restrict__ out, int N)
{
  __shared__ uint4 ldsB[NSTEP * 64];   // 43008 B

  const int tid  = threadIdx.x;
  const int lane = tid & 63;
  const int wv   = tid >> 6;          // wave 0..7
  const int h    = lane >> 5;         // K-half
  const int c32  = lane & 31;         // A row in tile / C column (mixture)
  const int blockRow = blockIdx.x * 256;

  // stage B fragments (contiguous 43 KB)
  const uint4* Bg = (const uint4*)Bws;
  for (int i = tid; i < NSTEP * 64; i += 512) ldsB[i] = Bg[i];

  // byte-selector: duplicate low half (h=0) or high half (h=1) of a half2 reg
  const unsigned sel = h ? 0x03020302u : 0x01000100u;

  const int rowi = blockRow + wv * 32 + c32;
  const int rowc = rowi < N ? rowi : N - 1;

  u32x16 xu;
  {
    const float4* xp = (const float4*)(X + (size_t)rowc * 32);
    #pragma unroll
    for (int q = 0; q < 8; ++q){
      float4 v = xp[q];
      xu[q*2+0] = pkrtz(v.x, v.y);     // v_cvt_pkrtz_f16_f32
      xu[q*2+1] = pkrtz(v.z, v.w);
    }
  }
  const float cc = cstg[c32];
  __syncthreads();

  f32x16 acc;
  #pragma unroll
  for (int i = 0; i < 16; ++i) acc[i] = 0.f;

  gsteps<0>((const f16x8*)ldsB, lane, h, sel, xu, acc);

  // epilogue: +cst, 32-lane column max, divide, store
  float nll[16], mx[16];
  #pragma unroll
  for (int r = 0; r < 16; ++r){
    float nv = acc[r] + cc;
    nll[r] = nv; mx[r] = nv;
  }
  #pragma unroll
  for (int md = 1; md <= 16; md <<= 1){
    #pragma unroll
    for (int r = 0; r < 16; ++r)
      mx[r] = fmaxf(mx[r], __shfl_xor(mx[r], md));
  }
  const int rowBase = blockRow + wv * 32;
  #pragma unroll
  for (int r = 0; r < 16; ++r){
    int row = (r & 3) + 8 * (r >> 2) + 4 * h;   // verified C/D mapping
    int n = rowBase + row;
    if (n < N) out[(size_t)n * 32 + c32] = nll[r] * __builtin_amdgcn_rcpf(mx[r]);
  }
}

extern "C" void kernel_launch(void* const* d_in, const int* in_sizes, int n_in,
                              void* d_out, int out_size, void* d_ws, size_t ws_size,
                              hipStream_t stream)
{
  const float* X      = (const float*)d_in[0];
  const float* mus    = (const float*)d_in[1];
  const float* sigmas = (const float*)d_in[2];
  const float* phis   = (const float*)d_in[3];
  float* out = (float*)d_out;
  const int N = in_sizes[0] / 32;

  unsigned short* Bws = (unsigned short*)d_ws;
  float* cstw = (float*)((char*)d_ws + NCHUNK * 256 * 2);   // +43008 B

  gmm_prep<<<32, 64, 0, stream>>>(mus, sigmas, phis, Bws, cstw);

  const int nb = (N + 255) / 256;
  gmm_main<<<nb, 512, 0, stream>>>(X, Bws, cstw, out, N);
}